// Round 11
// baseline (216.830 us; speedup 1.0000x reference)
//
#include <hip/hip_runtime.h>
#include <math.h>

#pragma clang fp contract(off)

// Problem constants (match reference)
#define PNUM 136500      // sum of f*f
#define HPNUM 68250      // PNUM/2 (exact)
#define BNUM 16
#define TOPK 5000
#define CAP 8192         // candidate capacity per image
#define NB4 4096         // histogram window buckets (ord>>14, covers (0.01, 1.0))
#define WBASE 0x2F000u   // window base: f2ord(0.01)>>14 = 0x2F08F >= 0x2F000
#define GCS 4            // gbcur counter stride (u32s)
#define NWORDS 79        // ceil(5000/64)
#define NW32 158         // 32-bit state words per image (NWORDS*2)
#define GSTRIDE 32       // ecnt padding: 32 u32 = 128 B per image
#define CAPE 65536       // edge capacity per image (expected E ~ 1-3k)
#define ELDS 14336       // LDS edge-copy capacity (56KB; global fallback beyond)
#define NXB 128          // spatial x1 buckets (major key)
#define NWC 8            // width classes per x1 bucket (minor key)
#define NYR 8            // y1 rows (tertiary key -> 4-slot groups share y-band)
#define NXB2 8192        // refined spatial buckets = NXB * NWC * NYR
#define BSTRIDE 5120     // per-image bucket-array stride (>= TOPK)
#define EBUF 3072        // per-block LDS edge buffer
#define SLOTS 4          // boxes per wave in k_pair4
#define SKI(i) ((i) + ((i) >> 4))   // LDS pad: kills bitonic bank conflicts

// Workspace layout (bytes). Zeroed range [OFF_HIST, OFF_ZEND) contiguous.
#define OFF_SC    ((size_t)0)                 // 320,000
#define OFF_BOX4  (OFF_SC + 320000)           // 1,280,000
#define OFF_HIST  (OFF_BOX4 + 1280000)        // 262,144
#define OFF_GBCUR (OFF_HIST + 262144)         // 1,048,576
#define OFF_ECNT  (OFF_GBCUR + 1048576)       // 2,048
#define OFF_BCNT  (OFF_ECNT + 2048)           // 16*8192*4 = 524,288
#define OFF_BCUR  (OFF_BCNT + 524288)         // 524,288
#define OFF_WCNT  (OFF_BCUR + 524288)         // 64
#define OFF_ZEND  (OFF_WCNT + 64)             // memset range end (~2.25 MB)
#define OFF_CUT   (OFF_ZEND)                  // 64
#define OFF_SBASE (OFF_CUT + 64)              // 262,144
#define OFF_WL    (OFF_SBASE + 262144)        // 262,144
#define OFF_KEYS  (OFF_WL + 262144)           // 1,048,576
#define OFF_EDGE  (OFF_KEYS + 1048576)        // 4,194,304
#define OFF_GRP   (OFF_EDGE + 4194304)        // overlay region for bucket arrays
#define OFF_BOFS  (OFF_GRP)                   // 16*130*4 (pad to 16384)
#define OFF_SIDX  (OFF_GRP + 16384)           // u32 [16*5120]
#define OFF_SBOX  (OFF_SIDX + 327680)         // float4 [16*5120]

__device__ __forceinline__ unsigned f2ord(float f) {
    unsigned u = __float_as_uint(f);
    return (u & 0x80000000u) ? ~u : (u | 0x80000000u);
}
__device__ __forceinline__ float ord2f(unsigned o) {
    unsigned u = (o & 0x80000000u) ? (o ^ 0x80000000u) : ~o;
    return __uint_as_float(u);
}
// monotone x1 -> bucket map; identical in k_ssortdec, k_bscat, k_pair4
__device__ __forceinline__ int bucketOf(float x) {
    int b = (int)((x + 0.6f) * 71.111115f);   // 128 buckets over [-0.6, 1.2]
    return (b < 0) ? 0 : ((b > 127) ? 127 : b);
}
// refined spatial key: x1-bucket major, width-class, y1-row minor.
// y-row grouping makes 4 consecutive slots share a narrow y-band so the
// group y-bounds early-out in k_pair4 rejects most candidates cheaply.
__device__ __forceinline__ int rkeyOf(float x1, float x2, float y1) {
    int b = bucketOf(x1);
    int wc = bucketOf(x2) - b;
    if (wc > NWC - 1) wc = NWC - 1;
    if (wc < 0) wc = 0;
    int yr = (int)((y1 + 0.6f) * 4.4444447f);  // 8 rows over [-0.6, 1.2]
    if (yr < 0) yr = 0;
    if (yr > NYR - 1) yr = NYR - 1;
    return (b * NWC + wc) * NYR + yr;
}

// K1: per-image histogram over the 4096-bucket (18-bit) window in LDS + merge.
__global__ void __launch_bounds__(512) k_hist(const float* __restrict__ conf,
                                              unsigned* __restrict__ hist) {
    __shared__ unsigned lh[NB4];
    int img = blockIdx.y;
    for (int i = threadIdx.x; i < NB4; i += 512) lh[i] = 0;
    __syncthreads();
    const float4* src = (const float4*)(conf + (size_t)img * PNUM * 2);
    int stride = gridDim.x * 512;
    for (int q = blockIdx.x * 512 + threadIdx.x; q < HPNUM; q += stride) {
        float4 v = src[q];
        if (v.y > 0.01f) atomicAdd(&lh[(f2ord(v.y) >> 14) - WBASE], 1u);
        if (v.w > 0.01f) atomicAdd(&lh[(f2ord(v.w) >> 14) - WBASE], 1u);
    }
    __syncthreads();
    unsigned* h = hist + (size_t)img * NB4;
    for (int i = threadIdx.x; i < NB4; i += 512) {
        unsigned c = lh[i];
        if (c) atomicAdd(&h[i], c);
    }
}

// K2: cutoff + per-bucket suffix base ranks over 4096 buckets; appends
// above-cut nonempty segments to a global worklist (kills dead sort blocks).
__global__ void __launch_bounds__(256) k_cutoff2(const unsigned* __restrict__ hist,
                                                 unsigned* __restrict__ cut,
                                                 unsigned* __restrict__ sbase,
                                                 unsigned* __restrict__ wl,
                                                 unsigned* __restrict__ wcnt) {
    __shared__ unsigned csum[256], suf[256], scut;
    int img = blockIdx.x;
    int t = threadIdx.x;
    const unsigned* h = hist + (size_t)img * NB4;
    unsigned hv[16];
    unsigned s = 0;
    #pragma unroll
    for (int j = 0; j < 16; ++j) { hv[j] = h[t * 16 + j]; s += hv[j]; }
    csum[t] = s;
    __syncthreads();
    if (t == 0) {
        unsigned a = 0;
        for (int g = 255; g >= 0; --g) { unsigned c = csum[g]; suf[g] = a; a += c; }
        unsigned acc = 0, before = 0;
        int c = -1;
        for (int cc = 255; cc >= 0; --cc) {
            if (acc + csum[cc] >= (unsigned)TOPK) { c = cc; before = acc; break; }
            acc += csum[cc];
        }
        unsigned cutb = WBASE;
        if (c >= 0) {
            unsigned s2 = before;
            cutb = WBASE + (unsigned)c * 16u;
            for (int b = c * 16 + 15; b >= c * 16; --b) {
                s2 += h[b];
                if (s2 >= (unsigned)TOPK) { cutb = WBASE + (unsigned)b; break; }
            }
        }
        scut = cutb;
        cut[img] = cutb;
    }
    __syncthreads();
    unsigned cutb = scut;
    unsigned acc = suf[t];
    unsigned* sb = sbase + (size_t)img * NB4 + t * 16;
    sb[15] = acc;
    #pragma unroll
    for (int j = 14; j >= 0; --j) { acc += hv[j + 1]; sb[j] = acc; }
    #pragma unroll
    for (int j = 0; j < 16; ++j) {
        unsigned b = (unsigned)t * 16u + (unsigned)j;
        if (WBASE + b >= cutb && hv[j] > 0) {
            unsigned x = atomicAdd(wcnt, 1u);
            wl[x] = ((unsigned)img << 12) | b;
        }
    }
}

// K3: gather candidates directly into their bucket segment (rank-scatter).
__global__ void __launch_bounds__(256) k_gather2(
        const float* __restrict__ conf, const unsigned* __restrict__ cut,
        const unsigned* __restrict__ sbase, unsigned* __restrict__ gbcur,
        unsigned long long* __restrict__ keys) {
    int q = blockIdx.x * 256 + threadIdx.x;
    int img = blockIdx.y;
    if (q >= HPNUM) return;
    unsigned cutb = cut[img];
    float4 v = ((const float4*)(conf + (size_t)img * PNUM * 2))[q];
    const unsigned* sb = sbase + (size_t)img * NB4;
    unsigned* gc = gbcur + (size_t)img * NB4 * GCS;
    unsigned long long* kp = keys + (size_t)img * CAP;
    #pragma unroll
    for (int e = 0; e < 2; ++e) {
        float s = e ? v.w : v.y;
        if (s > 0.01f) {
            unsigned o = f2ord(s);
            unsigned w18 = o >> 14;
            if (w18 >= cutb) {
                unsigned wb = w18 - WBASE;
                unsigned pos = sb[wb] + atomicAdd(&gc[wb * GCS], 1u);
                if (pos < (unsigned)CAP)
                    kp[pos] = ((unsigned long long)o << 32)
                              | (unsigned)(~(unsigned)(2 * q + e));
            }
        }
    }
}

// K4: worklist-driven fused per-segment sort + decode + spatial-bucket count.
__global__ void __launch_bounds__(256) k_ssortdec(
        const unsigned long long* __restrict__ keys,
        const unsigned* __restrict__ hist, const unsigned* __restrict__ sbase,
        const unsigned* __restrict__ wl, const unsigned* __restrict__ wcnt,
        const float* __restrict__ loc, const float* __restrict__ pri,
        float* __restrict__ SC, float4* __restrict__ BOX4,
        unsigned* __restrict__ bcnt) {
    __shared__ unsigned long long sk[1088];       // 1024 + pad
    __shared__ unsigned lhist[NXB2];              // 32 KiB
    int tid = threadIdx.x;
    unsigned nW = *wcnt;
    for (unsigned w = blockIdx.x; w < nW; w += gridDim.x) {
        unsigned ent = wl[w];
        int img = (int)(ent >> 12);
        int b = (int)(ent & 4095u);
        unsigned cnt = hist[(size_t)img * NB4 + b];
        unsigned base = sbase[(size_t)img * NB4 + b];
        if (base >= (unsigned)TOPK) continue;     // uniform (defensive)
        const unsigned long long* kp = keys + (size_t)img * CAP + base;
        for (int i = tid; i < NXB2; i += 256) lhist[i] = 0;
        unsigned scnt = cnt > 1024 ? 1024u : cnt; // sorted prefix
        if (scnt >= 2) {
            unsigned np2 = 2;
            while (np2 < scnt) np2 <<= 1;         // block-uniform
            for (unsigned i = tid; i < np2; i += 256)
                sk[SKI(i)] = (i < scnt) ? kp[i] : 0ull;
            __syncthreads();
            for (unsigned k = 2; k <= np2; k <<= 1) {
                for (unsigned j = k >> 1; j > 0; j >>= 1) {
                    for (unsigned t = tid; t < (np2 >> 1); t += 256) {
                        unsigned i = ((t & ~(j - 1)) << 1) | (t & (j - 1));
                        unsigned p = i | j;
                        bool desc = ((i & k) == 0);
                        unsigned long long a = sk[SKI(i)], bb = sk[SKI(p)];
                        bool sw = desc ? (a < bb) : (a > bb);
                        if (sw) { sk[SKI(i)] = bb; sk[SKI(p)] = a; }
                    }
                    __syncthreads();
                }
            }
        } else {
            if (tid == 0 && scnt == 1) sk[0] = kp[0];
            __syncthreads();
        }
        // decode (identical arithmetic to the original; contract off)
        size_t ibase = (size_t)img * TOPK;
        for (unsigned i = tid; i < cnt; i += 256) {
            unsigned r = base + i;
            if (r >= (unsigned)TOPK) continue;    // only cut-segment tail
            unsigned long long key = (i < scnt) ? sk[SKI(i)] : kp[i];
            float s, x1, y1, x2, y2;
            if (key != 0ull) {
                unsigned ordv = (unsigned)(key >> 32);
                s = ord2f(ordv);
                unsigned p = ~(unsigned)(key & 0xFFFFFFFFull);
                const float* lp = loc + ((size_t)img * PNUM + p) * 4;
                const float* pp = pri + (size_t)p * 4;
                float lx = lp[0], ly = lp[1], lw = lp[2], lh = lp[3];
                float px = pp[0], py = pp[1], pw = pp[2], ph = pp[3];
                float cx = px + (lx * 0.1f) * pw;
                float cy = py + (ly * 0.1f) * ph;
                float w2 = pw * expf(lw * 0.2f);
                float h2 = ph * expf(lh * 0.2f);
                x1 = cx - w2 * 0.5f;
                y1 = cy - h2 * 0.5f;
                x2 = x1 + w2;
                y2 = y1 + h2;
            } else {
                s = -1.0f; x1 = 0.f; y1 = 0.f; x2 = 0.f; y2 = 0.f;
            }
            SC[ibase + r] = s;
            BOX4[ibase + r] = make_float4(x1, y1, x2, y2);
            atomicAdd(&lhist[rkeyOf(x1, x2, y1)], 1u);
        }
        __syncthreads();
        for (int i = tid; i < NXB2; i += 256) {
            unsigned c = lhist[i];
            if (c) atomicAdd(&bcnt[img * NXB2 + i], c);
        }
        __syncthreads();                          // before lhist/sk reuse
    }
}

// K6: wide bucket scatter over refined spatial keys; also zeroes the output
// slice for its image (320 wide blocks vs 16-block k_nms3 -- off critical
// path). Intra-bucket order arbitrary -> edge set unchanged.
__global__ void __launch_bounds__(256) k_bscat(
        const unsigned* __restrict__ bcnt, unsigned* __restrict__ bcur,
        const float4* __restrict__ BOX4,
        unsigned* __restrict__ bofs, unsigned* __restrict__ sidx,
        float4* __restrict__ sbox, float* __restrict__ out) {
    __shared__ unsigned bpre[NXB2 + 1], tsum[256];
    int img = blockIdx.y;
    int tid = threadIdx.x;
    // zero output slice: 2*5000*5 floats = 12500 uint4 over 20 blocks
    uint4* oz = (uint4*)(out + (size_t)img * 2 * TOPK * 5);
    uint4 z4 = make_uint4(0u, 0u, 0u, 0u);
    for (int i = blockIdx.x * 256 + tid; i < 12500; i += 20 * 256) oz[i] = z4;
    const unsigned* bc = bcnt + (size_t)img * NXB2;
    unsigned lv[32];
    unsigned s = 0;
    #pragma unroll
    for (int j = 0; j < 32; ++j) { lv[j] = bc[tid * 32 + j]; s += lv[j]; }
    tsum[tid] = s;
    __syncthreads();
    if (tid == 0) {
        unsigned a = 0;
        for (int t = 0; t < 256; ++t) { unsigned c = tsum[t]; tsum[t] = a; a += c; }
        bpre[NXB2] = a;
    }
    __syncthreads();
    unsigned a = tsum[tid];
    #pragma unroll
    for (int j = 0; j < 32; ++j) { bpre[tid * 32 + j] = a; a += lv[j]; }
    __syncthreads();
    if (blockIdx.x == 0) {
        if (tid < NXB) bofs[img * 130 + tid] = bpre[tid * (NWC * NYR)];
        if (tid == 0) bofs[img * 130 + NXB] = bpre[NXB2];
    }
    int r = blockIdx.x * 256 + tid;
    if (r < TOPK) {
        float4 b = BOX4[(size_t)img * TOPK + r];
        int bk = rkeyOf(b.x, b.z, b.y);
        unsigned sp = bpre[bk] + atomicAdd(&bcur[(size_t)img * NXB2 + bk], 1u);
        int base = img * BSTRIDE;
        sidx[base + sp] = (unsigned)r;
        sbox[base + sp] = b;
    }
}

// K7: 4-slot-per-wave bucketed pair search. y-row tertiary key upstream means
// 4 consecutive slots share a narrow y-band; the group y-bounds early-out
// rejects provably-dy<=0 candidates after 2 compares (edge set identical).
__global__ void __launch_bounds__(256) k_pair4(
        const unsigned* __restrict__ bofs, const unsigned* __restrict__ sidx,
        const float4* __restrict__ sbox,
        unsigned* __restrict__ ecnt, unsigned* __restrict__ edges) {
    __shared__ unsigned ebuf[EBUF];
    __shared__ unsigned ecl, ebase;
    int img = blockIdx.y;
    int wid = threadIdx.x >> 6;
    int lane = threadIdx.x & 63;
    int sb0 = (blockIdx.x * 4 + wid) * SLOTS;     // first of SLOTS slots
    if (threadIdx.x == 0) ecl = 0;
    __syncthreads();
    unsigned* ec = ecnt + (size_t)img * GSTRIDE;
    unsigned* eg = edges + (size_t)img * CAPE;
    if (sb0 < TOPK) {
        int base = img * BSTRIDE;
        float x1k[SLOTS], x2k[SLOTS], y1k[SLOTS], y2k[SLOTS], ark[SLOTS];
        unsigned rk[SLOTS];
        bool act[SLOTS];
        #pragma unroll
        for (int k = 0; k < SLOTS; ++k) {
            act[k] = (sb0 + k) < TOPK;
            int s = act[k] ? (sb0 + k) : sb0;
            float4 bk = sbox[base + s];
            x1k[k] = bk.x; y1k[k] = bk.y; x2k[k] = bk.z; y2k[k] = bk.w;
            ark[k] = (bk.z - bk.x) * (bk.w - bk.y);
            rk[k] = sidx[base + s];
        }
        int b1 = bucketOf(x1k[0]);                // min bucket (slot-monotone)
        int b2m = bucketOf(x2k[0]);
        float gymin = y1k[0], gymax = y2k[0];
        #pragma unroll
        for (int k = 1; k < SLOTS; ++k)
            if (act[k]) {
                int b = bucketOf(x2k[k]); if (b > b2m) b2m = b;
                gymin = fminf(gymin, y1k[k]);
                gymax = fmaxf(gymax, y2k[k]);
            }
        const unsigned* bo = bofs + img * 130;
        unsigned s0 = bo[b1], s1 = bo[b2m + 1];
        if (s0 < s1) {
            unsigned nit = (s1 - s0 + 63) >> 6;
            unsigned c0 = s0 + (unsigned)lane;
            if (c0 > s1 - 1) c0 = s1 - 1;         // clamp: always valid
            float4 cb = sbox[base + c0];
            unsigned cr = sidx[base + c0];
            for (unsigned it = 0; it < nit; ++it) {
                float4 nb = cb; unsigned nr = cr;
                if (it + 1 < nit) {               // uniform prefetch
                    unsigned cn = s0 + (it + 1) * 64 + (unsigned)lane;
                    if (cn > s1 - 1) cn = s1 - 1;
                    nb = sbox[base + cn];
                    nr = sidx[base + cn];
                }
                bool in = (s0 + it * 64 + (unsigned)lane) < s1;
                // group y early-out: if cb.w <= gymin or cb.y >= gymax then
                // dy <= 0 for every slot -> safe reject (edge set unchanged)
                bool yok = in && (cb.w > gymin) && (cb.y < gymax);
                float bar = (cb.z - cb.x) * (cb.w - cb.y);
                #pragma unroll
                for (int k = 0; k < SLOTS; ++k) {
                    bool hit = false;
                    unsigned edge = 0;
                    if (yok && act[k] && cb.x >= x1k[k]
                        && !(cb.x == x1k[k] && cr <= rk[k])) {
                        float dx = fminf(x2k[k], cb.z) - fmaxf(x1k[k], cb.x);
                        if (dx > 0.0f) {
                            float dy = fminf(y2k[k], cb.w) - fmaxf(y1k[k], cb.y);
                            if (dy > 0.0f) {
                                float inter = dx * dy;
                                float iou = inter / (bar + ark[k] - inter);
                                if (iou > 0.3f) {
                                    unsigned su = (rk[k] < cr) ? rk[k] : cr;
                                    unsigned vi = (rk[k] < cr) ? cr : rk[k];
                                    edge = (vi << 13) | su;
                                    hit = true;
                                }
                            }
                        }
                    }
                    unsigned long long bal = __ballot(hit);
                    if (bal) {
                        int n = __popcll(bal);
                        unsigned wb = 0;
                        if (lane == 0) wb = atomicAdd(&ecl, (unsigned)n);
                        wb = __shfl(wb, 0, 64);
                        if (hit) {
                            unsigned long long lt =
                                (lane == 0) ? 0ull : ((1ull << lane) - 1ull);
                            unsigned p = wb + (unsigned)__popcll(bal & lt);
                            if (p < (unsigned)EBUF) ebuf[p] = edge;
                            else {
                                unsigned gp = atomicAdd(ec, 1u);
                                if (gp < (unsigned)CAPE) eg[gp] = edge;
                            }
                        }
                    }
                }
                cb = nb; cr = nr;
            }
        }
    }
    __syncthreads();
    unsigned n = min(ecl, (unsigned)EBUF);
    if (threadIdx.x == 0 && n) ebase = atomicAdd(ec, n);
    __syncthreads();
    for (unsigned i = threadIdx.x; i < n; i += 256) {
        unsigned p = ebase + i;
        if (p < (unsigned)CAPE) eg[p] = ebuf[i];
    }
}

// K8: edge-parallel monotone fixpoint NMS resolve + compaction. Output slice
// already zeroed by k_bscat. ELDS raised to 14336 (56 KiB) so larger edge
// sets stay LDS-resident across rounds.
__global__ void __launch_bounds__(256) k_nms3(
        const float* __restrict__ SC, const float4* __restrict__ BOX4,
        const unsigned* __restrict__ ecnt, const unsigned* __restrict__ edges,
        float* __restrict__ out) {
    __shared__ unsigned lgrp[ELDS];               // 56 KiB raw edge copy
    __shared__ unsigned undL[160], keptL[160], blockL[160];
    __shared__ unsigned pfx[80];
    __shared__ int chg[2];
    int img = blockIdx.x;
    int tid = threadIdx.x;
    int l = tid & 63;
    int wid = tid >> 6;
    size_t ib = (size_t)img * TOPK;
    const float* sc = SC + ib;

    if (tid < 160) { keptL[tid] = 0u; blockL[tid] = 0u; }
    if (tid < 2) chg[tid] = 0;
    for (int w = wid; w < NWORDS; w += 4) {
        int row = w * 64 + l;
        bool valid = (row < TOPK) && (sc[row] > 0.01f);
        unsigned long long b = __ballot(valid);
        if (l == 0) {
            undL[2 * w]     = (unsigned)b;
            undL[2 * w + 1] = (unsigned)(b >> 32);
        }
    }
    unsigned E = min(ecnt[(size_t)img * GSTRIDE], (unsigned)CAPE);
    const unsigned* eimg = edges + (size_t)img * CAPE;
    bool inl = (E <= (unsigned)ELDS);             // uniform across block
    if (inl) for (unsigned e = tid; e < E; e += 256) lgrp[e] = eimg[e];
    __syncthreads();

    for (int round = 0; round < 256; ++round) {
        int par = round & 1;
        for (unsigned e = tid; e < E; e += 256) {
            unsigned ed = inl ? lgrp[e] : eimg[e];
            unsigned s = ed & 8191u;
            unsigned v = ed >> 13;
            unsigned sw = s >> 5, sb = s & 31u;
            unsigned vw = v >> 5, vb = 1u << (v & 31u);
            if ((keptL[sw] >> sb) & 1u) {
                if (undL[vw] & vb) {
                    unsigned old = atomicAnd(&undL[vw], ~vb);
                    if (old & vb) chg[par] = 1;   // a real kill happened
                }
            } else if ((undL[sw] >> sb) & 1u) {
                if (!(blockL[vw] & vb)) atomicOr(&blockL[vw], vb);
            }
        }
        __syncthreads();
        if (tid < NW32) {
            unsigned nk = undL[tid] & ~blockL[tid];
            if (nk) {
                keptL[tid] |= nk;
                undL[tid] &= ~nk;
                chg[par] = 1;
            }
            blockL[tid] = 0u;
        }
        if (tid == 0) chg[par ^ 1] = 0;           // pre-zero next round's flag
        __syncthreads();
        if (!chg[par]) break;                     // uniform
    }

    if (tid == 0) {
        unsigned acc = 0;
        for (int w = 0; w < NWORDS; ++w) {
            pfx[w] = acc;
            acc += (unsigned)(__popc(keptL[2 * w]) + __popc(keptL[2 * w + 1]));
        }
    }
    __syncthreads();
    const float4* bx = BOX4 + ib;
    float* op = out + (((size_t)img * 2) + 1) * TOPK * 5;
    for (int w = wid; w < NWORDS; w += 4) {
        unsigned long long kw =
            ((unsigned long long)keptL[2 * w + 1] << 32) | keptL[2 * w];
        if (!kw) continue;
        int row = w * 64 + l;
        if ((kw >> l) & 1ull) {
            int rank = (int)pfx[w] + (int)__popcll(kw & ((1ull << l) - 1ull));
            float4 b = bx[row];
            float* r = op + (size_t)rank * 5;
            r[0] = sc[row]; r[1] = b.x; r[2] = b.y; r[3] = b.z; r[4] = b.w;
        }
    }
}

extern "C" void kernel_launch(void* const* d_in, const int* in_sizes, int n_in,
                              void* d_out, int out_size, void* d_ws, size_t ws_size,
                              hipStream_t stream) {
    (void)in_sizes; (void)n_in; (void)ws_size; (void)out_size;
    const float* loc  = (const float*)d_in[0];   // (16, 136500, 4)
    const float* conf = (const float*)d_in[1];   // (16*136500, 2)
    const float* pri  = (const float*)d_in[2];   // (136500, 4)
    float* out = (float*)d_out;                  // (16, 2, 5000, 5)
    char* ws = (char*)d_ws;

    float* SC   = (float*)(ws + OFF_SC);
    float4* BOX4 = (float4*)(ws + OFF_BOX4);
    unsigned* hist = (unsigned*)(ws + OFF_HIST);
    unsigned* cut  = (unsigned*)(ws + OFF_CUT);
    unsigned* sbase = (unsigned*)(ws + OFF_SBASE);
    unsigned* gbcur = (unsigned*)(ws + OFF_GBCUR);
    unsigned long long* keys = (unsigned long long*)(ws + OFF_KEYS);
    unsigned* ecnt = (unsigned*)(ws + OFF_ECNT);
    unsigned* bcnt = (unsigned*)(ws + OFF_BCNT);
    unsigned* bcur = (unsigned*)(ws + OFF_BCUR);
    unsigned* wcnt = (unsigned*)(ws + OFF_WCNT);
    unsigned* wl   = (unsigned*)(ws + OFF_WL);
    unsigned* edges = (unsigned*)(ws + OFF_EDGE);
    unsigned* bofs = (unsigned*)(ws + OFF_BOFS);
    unsigned* sidx = (unsigned*)(ws + OFF_SIDX);
    float4* sbox = (float4*)(ws + OFF_SBOX);

    // single contiguous zero: hist, gbcur, ecnt, bcnt, bcur, wcnt
    hipMemsetAsync(ws + OFF_HIST, 0, OFF_ZEND - OFF_HIST, stream);

    dim3 gh1(32, BNUM);                          // 32 grid-stride blocks/image
    k_hist<<<gh1, 512, 0, stream>>>(conf, hist);
    k_cutoff2<<<BNUM, 256, 0, stream>>>(hist, cut, sbase, wl, wcnt);
    dim3 gh2((HPNUM + 255) / 256, BNUM);
    k_gather2<<<gh2, 256, 0, stream>>>(conf, cut, sbase, gbcur, keys);
    k_ssortdec<<<1024, 256, 0, stream>>>(keys, hist, sbase, wl, wcnt,
                                         loc, pri, SC, BOX4, bcnt);
    dim3 gb((TOPK + 255) / 256, BNUM);           // wide bucket scatter + out-zero
    k_bscat<<<gb, 256, 0, stream>>>(bcnt, bcur, BOX4, bofs, sidx, sbox, out);
    dim3 pg((TOPK + 4 * SLOTS - 1) / (4 * SLOTS), BNUM);  // 4 waves x 4 slots
    k_pair4<<<pg, 256, 0, stream>>>(bofs, sidx, sbox, ecnt, edges);
    k_nms3<<<BNUM, 256, 0, stream>>>(SC, BOX4, ecnt, edges, out);
}

// Round 12
// 212.103 us; speedup vs baseline: 1.0223x; 1.0223x over previous
//
#include <hip/hip_runtime.h>
#include <math.h>

#pragma clang fp contract(off)

// Problem constants (match reference)
#define PNUM 136500      // sum of f*f
#define HPNUM 68250      // PNUM/2 (exact)
#define BNUM 16
#define TOPK 5000
#define CAP 8192         // candidate capacity per image
#define NB4 4096         // histogram window buckets (ord>>14, covers (0.01, 1.0))
#define WBASE 0x2F000u   // window base: f2ord(0.01)>>14 = 0x2F08F >= 0x2F000
#define GCS 4            // gbcur counter stride (u32s)
#define NWORDS 79        // ceil(5000/64)
#define NW32 158         // 32-bit state words per image (NWORDS*2)
#define GSTRIDE 32       // ecnt padding: 32 u32 = 128 B per image
#define CAPE 65536       // edge capacity per image (expected E ~ 1-3k)
#define ELDS 14336       // LDS edge-copy capacity (56KB; global fallback beyond)
#define NXB 128          // spatial x1 buckets (major key)
#define NWC 8            // width classes per x1 bucket (minor key)
#define NXB2 1024        // refined spatial buckets = NXB * NWC
#define BSTRIDE 5120     // per-image bucket-array stride (>= TOPK)
#define EBUF 3072        // per-block LDS edge buffer
#define SLOTS 4          // boxes per wave in k_pair4
#define SKI(i) ((i) + ((i) >> 4))   // LDS pad: kills bitonic bank conflicts

// Workspace layout (bytes). Zeroed range [OFF_HIST, OFF_ZEND) contiguous.
#define OFF_SC    ((size_t)0)                 // 320,000
#define OFF_BOX4  (OFF_SC + 320000)           // 1,280,000
#define OFF_HIST  (OFF_BOX4 + 1280000)        // 262,144
#define OFF_GBCUR (OFF_HIST + 262144)         // 1,048,576
#define OFF_ECNT  (OFF_GBCUR + 1048576)       // 2,048
#define OFF_BCNT  (OFF_ECNT + 2048)           // 16*1024*4 = 65,536
#define OFF_BCUR  (OFF_BCNT + 65536)          // 65,536
#define OFF_WCNT  (OFF_BCUR + 65536)          // 64
#define OFF_ZEND  (OFF_WCNT + 64)             // memset range end
#define OFF_CUT   (OFF_ZEND)                  // 64
#define OFF_SBASE (OFF_CUT + 64)              // 262,144
#define OFF_WL    (OFF_SBASE + 262144)        // 262,144
#define OFF_KEYS  (OFF_WL + 262144)           // 1,048,576
#define OFF_EDGE  (OFF_KEYS + 1048576)        // 4,194,304
#define OFF_GRP   (OFF_EDGE + 4194304)        // overlay region for bucket arrays
#define OFF_BOFS  (OFF_GRP)                   // 16*130*4 (pad to 16384)
#define OFF_SIDX  (OFF_GRP + 16384)           // u32 [16*5120]
#define OFF_SBOX  (OFF_SIDX + 327680)         // float4 [16*5120]

__device__ __forceinline__ unsigned f2ord(float f) {
    unsigned u = __float_as_uint(f);
    return (u & 0x80000000u) ? ~u : (u | 0x80000000u);
}
__device__ __forceinline__ float ord2f(unsigned o) {
    unsigned u = (o & 0x80000000u) ? (o ^ 0x80000000u) : ~o;
    return __uint_as_float(u);
}
// monotone x1 -> bucket map; identical in k_ssortdec, k_bscat, k_pair4
__device__ __forceinline__ int bucketOf(float x) {
    int b = (int)((x + 0.6f) * 71.111115f);   // 128 buckets over [-0.6, 1.2]
    return (b < 0) ? 0 : ((b > 127) ? 127 : b);
}
// refined spatial key: x1-bucket major, width-class minor (R10 form; the
// y-row tertiary key regressed: 8x lhist zero+merge in k_ssortdec)
__device__ __forceinline__ int rkeyOf(float x1, float x2) {
    int b = bucketOf(x1);
    int wc = bucketOf(x2) - b;
    if (wc > NWC - 1) wc = NWC - 1;
    if (wc < 0) wc = 0;
    return b * NWC + wc;
}

// K1: per-image histogram over the 4096-bucket (18-bit) window in LDS + merge.
__global__ void __launch_bounds__(512) k_hist(const float* __restrict__ conf,
                                              unsigned* __restrict__ hist) {
    __shared__ unsigned lh[NB4];
    int img = blockIdx.y;
    for (int i = threadIdx.x; i < NB4; i += 512) lh[i] = 0;
    __syncthreads();
    const float4* src = (const float4*)(conf + (size_t)img * PNUM * 2);
    int stride = gridDim.x * 512;
    for (int q = blockIdx.x * 512 + threadIdx.x; q < HPNUM; q += stride) {
        float4 v = src[q];
        if (v.y > 0.01f) atomicAdd(&lh[(f2ord(v.y) >> 14) - WBASE], 1u);
        if (v.w > 0.01f) atomicAdd(&lh[(f2ord(v.w) >> 14) - WBASE], 1u);
    }
    __syncthreads();
    unsigned* h = hist + (size_t)img * NB4;
    for (int i = threadIdx.x; i < NB4; i += 512) {
        unsigned c = lh[i];
        if (c) atomicAdd(&h[i], c);
    }
}

// K2: cutoff + per-bucket suffix base ranks over 4096 buckets; appends
// above-cut nonempty segments to a global worklist (kills dead sort blocks).
__global__ void __launch_bounds__(256) k_cutoff2(const unsigned* __restrict__ hist,
                                                 unsigned* __restrict__ cut,
                                                 unsigned* __restrict__ sbase,
                                                 unsigned* __restrict__ wl,
                                                 unsigned* __restrict__ wcnt) {
    __shared__ unsigned csum[256], suf[256], scut;
    int img = blockIdx.x;
    int t = threadIdx.x;
    const unsigned* h = hist + (size_t)img * NB4;
    unsigned hv[16];
    unsigned s = 0;
    #pragma unroll
    for (int j = 0; j < 16; ++j) { hv[j] = h[t * 16 + j]; s += hv[j]; }
    csum[t] = s;
    __syncthreads();
    if (t == 0) {
        unsigned a = 0;
        for (int g = 255; g >= 0; --g) { unsigned c = csum[g]; suf[g] = a; a += c; }
        unsigned acc = 0, before = 0;
        int c = -1;
        for (int cc = 255; cc >= 0; --cc) {
            if (acc + csum[cc] >= (unsigned)TOPK) { c = cc; before = acc; break; }
            acc += csum[cc];
        }
        unsigned cutb = WBASE;
        if (c >= 0) {
            unsigned s2 = before;
            cutb = WBASE + (unsigned)c * 16u;
            for (int b = c * 16 + 15; b >= c * 16; --b) {
                s2 += h[b];
                if (s2 >= (unsigned)TOPK) { cutb = WBASE + (unsigned)b; break; }
            }
        }
        scut = cutb;
        cut[img] = cutb;
    }
    __syncthreads();
    unsigned cutb = scut;
    unsigned acc = suf[t];
    unsigned* sb = sbase + (size_t)img * NB4 + t * 16;
    sb[15] = acc;
    #pragma unroll
    for (int j = 14; j >= 0; --j) { acc += hv[j + 1]; sb[j] = acc; }
    #pragma unroll
    for (int j = 0; j < 16; ++j) {
        unsigned b = (unsigned)t * 16u + (unsigned)j;
        if (WBASE + b >= cutb && hv[j] > 0) {
            unsigned x = atomicAdd(wcnt, 1u);
            wl[x] = ((unsigned)img << 12) | b;
        }
    }
}

// K3: gather candidates directly into their bucket segment (rank-scatter).
__global__ void __launch_bounds__(256) k_gather2(
        const float* __restrict__ conf, const unsigned* __restrict__ cut,
        const unsigned* __restrict__ sbase, unsigned* __restrict__ gbcur,
        unsigned long long* __restrict__ keys) {
    int q = blockIdx.x * 256 + threadIdx.x;
    int img = blockIdx.y;
    if (q >= HPNUM) return;
    unsigned cutb = cut[img];
    float4 v = ((const float4*)(conf + (size_t)img * PNUM * 2))[q];
    const unsigned* sb = sbase + (size_t)img * NB4;
    unsigned* gc = gbcur + (size_t)img * NB4 * GCS;
    unsigned long long* kp = keys + (size_t)img * CAP;
    #pragma unroll
    for (int e = 0; e < 2; ++e) {
        float s = e ? v.w : v.y;
        if (s > 0.01f) {
            unsigned o = f2ord(s);
            unsigned w18 = o >> 14;
            if (w18 >= cutb) {
                unsigned wb = w18 - WBASE;
                unsigned pos = sb[wb] + atomicAdd(&gc[wb * GCS], 1u);
                if (pos < (unsigned)CAP)
                    kp[pos] = ((unsigned long long)o << 32)
                              | (unsigned)(~(unsigned)(2 * q + e));
            }
        }
    }
}

// K4: worklist-driven fused per-segment sort + decode + spatial-bucket count.
__global__ void __launch_bounds__(256) k_ssortdec(
        const unsigned long long* __restrict__ keys,
        const unsigned* __restrict__ hist, const unsigned* __restrict__ sbase,
        const unsigned* __restrict__ wl, const unsigned* __restrict__ wcnt,
        const float* __restrict__ loc, const float* __restrict__ pri,
        float* __restrict__ SC, float4* __restrict__ BOX4,
        unsigned* __restrict__ bcnt) {
    __shared__ unsigned long long sk[1088];       // 1024 + pad
    __shared__ unsigned lhist[NXB2];
    int tid = threadIdx.x;
    unsigned nW = *wcnt;
    for (unsigned w = blockIdx.x; w < nW; w += gridDim.x) {
        unsigned ent = wl[w];
        int img = (int)(ent >> 12);
        int b = (int)(ent & 4095u);
        unsigned cnt = hist[(size_t)img * NB4 + b];
        unsigned base = sbase[(size_t)img * NB4 + b];
        if (base >= (unsigned)TOPK) continue;     // uniform (defensive)
        const unsigned long long* kp = keys + (size_t)img * CAP + base;
        for (int i = tid; i < NXB2; i += 256) lhist[i] = 0;
        unsigned scnt = cnt > 1024 ? 1024u : cnt; // sorted prefix
        if (scnt >= 2) {
            unsigned np2 = 2;
            while (np2 < scnt) np2 <<= 1;         // block-uniform
            for (unsigned i = tid; i < np2; i += 256)
                sk[SKI(i)] = (i < scnt) ? kp[i] : 0ull;
            __syncthreads();
            for (unsigned k = 2; k <= np2; k <<= 1) {
                for (unsigned j = k >> 1; j > 0; j >>= 1) {
                    for (unsigned t = tid; t < (np2 >> 1); t += 256) {
                        unsigned i = ((t & ~(j - 1)) << 1) | (t & (j - 1));
                        unsigned p = i | j;
                        bool desc = ((i & k) == 0);
                        unsigned long long a = sk[SKI(i)], bb = sk[SKI(p)];
                        bool sw = desc ? (a < bb) : (a > bb);
                        if (sw) { sk[SKI(i)] = bb; sk[SKI(p)] = a; }
                    }
                    __syncthreads();
                }
            }
        } else {
            if (tid == 0 && scnt == 1) sk[0] = kp[0];
            __syncthreads();
        }
        // decode (identical arithmetic to the original; contract off)
        size_t ibase = (size_t)img * TOPK;
        for (unsigned i = tid; i < cnt; i += 256) {
            unsigned r = base + i;
            if (r >= (unsigned)TOPK) continue;    // only cut-segment tail
            unsigned long long key = (i < scnt) ? sk[SKI(i)] : kp[i];
            float s, x1, y1, x2, y2;
            if (key != 0ull) {
                unsigned ordv = (unsigned)(key >> 32);
                s = ord2f(ordv);
                unsigned p = ~(unsigned)(key & 0xFFFFFFFFull);
                const float* lp = loc + ((size_t)img * PNUM + p) * 4;
                const float* pp = pri + (size_t)p * 4;
                float lx = lp[0], ly = lp[1], lw = lp[2], lh = lp[3];
                float px = pp[0], py = pp[1], pw = pp[2], ph = pp[3];
                float cx = px + (lx * 0.1f) * pw;
                float cy = py + (ly * 0.1f) * ph;
                float w2 = pw * expf(lw * 0.2f);
                float h2 = ph * expf(lh * 0.2f);
                x1 = cx - w2 * 0.5f;
                y1 = cy - h2 * 0.5f;
                x2 = x1 + w2;
                y2 = y1 + h2;
            } else {
                s = -1.0f; x1 = 0.f; y1 = 0.f; x2 = 0.f; y2 = 0.f;
            }
            SC[ibase + r] = s;
            BOX4[ibase + r] = make_float4(x1, y1, x2, y2);
            atomicAdd(&lhist[rkeyOf(x1, x2)], 1u);
        }
        __syncthreads();
        for (int i = tid; i < NXB2; i += 256) {
            unsigned c = lhist[i];
            if (c) atomicAdd(&bcnt[img * NXB2 + i], c);
        }
        __syncthreads();                          // before lhist/sk reuse
    }
}

// K6: wide bucket scatter over refined spatial keys; also zeroes the output
// slice for its image (320 wide blocks, off critical path).
__global__ void __launch_bounds__(256) k_bscat(
        const unsigned* __restrict__ bcnt, unsigned* __restrict__ bcur,
        const float4* __restrict__ BOX4,
        unsigned* __restrict__ bofs, unsigned* __restrict__ sidx,
        float4* __restrict__ sbox, float* __restrict__ out) {
    __shared__ unsigned bpre[NXB2 + 1], tsum[256];
    int img = blockIdx.y;
    int tid = threadIdx.x;
    // zero output slice: 2*5000*5 floats = 12500 uint4 over 20 blocks
    uint4* oz = (uint4*)(out + (size_t)img * 2 * TOPK * 5);
    uint4 z4 = make_uint4(0u, 0u, 0u, 0u);
    for (int i = blockIdx.x * 256 + tid; i < 12500; i += 20 * 256) oz[i] = z4;
    const unsigned* bc = bcnt + img * NXB2;
    unsigned l0 = bc[tid * 4], l1 = bc[tid * 4 + 1],
             l2 = bc[tid * 4 + 2], l3 = bc[tid * 4 + 3];
    tsum[tid] = l0 + l1 + l2 + l3;
    __syncthreads();
    if (tid == 0) {
        unsigned a = 0;
        for (int t = 0; t < 256; ++t) { unsigned c = tsum[t]; tsum[t] = a; a += c; }
        bpre[NXB2] = a;
    }
    __syncthreads();
    unsigned a = tsum[tid];
    bpre[tid * 4] = a;
    bpre[tid * 4 + 1] = a + l0;
    bpre[tid * 4 + 2] = a + l0 + l1;
    bpre[tid * 4 + 3] = a + l0 + l1 + l2;
    __syncthreads();
    if (blockIdx.x == 0) {
        if (tid < NXB) bofs[img * 130 + tid] = bpre[tid * NWC];
        if (tid == 0) bofs[img * 130 + NXB] = bpre[NXB2];
    }
    int r = blockIdx.x * 256 + tid;
    if (r < TOPK) {
        float4 b = BOX4[(size_t)img * TOPK + r];
        int bk = rkeyOf(b.x, b.z);
        unsigned sp = bpre[bk] + atomicAdd(&bcur[img * NXB2 + bk], 1u);
        int base = img * BSTRIDE;
        sidx[base + sp] = (unsigned)r;
        sbox[base + sp] = b;
    }
}

// K7: 4-slot-per-wave bucketed pair search with packed float4 candidates,
// register double-buffer prefetch, and group y-bounds early-out (rejects
// only provably-dy<=0 candidates -> edge set identical).
__global__ void __launch_bounds__(256) k_pair4(
        const unsigned* __restrict__ bofs, const unsigned* __restrict__ sidx,
        const float4* __restrict__ sbox,
        unsigned* __restrict__ ecnt, unsigned* __restrict__ edges) {
    __shared__ unsigned ebuf[EBUF];
    __shared__ unsigned ecl, ebase;
    int img = blockIdx.y;
    int wid = threadIdx.x >> 6;
    int lane = threadIdx.x & 63;
    int sb0 = (blockIdx.x * 4 + wid) * SLOTS;     // first of SLOTS slots
    if (threadIdx.x == 0) ecl = 0;
    __syncthreads();
    unsigned* ec = ecnt + (size_t)img * GSTRIDE;
    unsigned* eg = edges + (size_t)img * CAPE;
    if (sb0 < TOPK) {
        int base = img * BSTRIDE;
        float x1k[SLOTS], x2k[SLOTS], y1k[SLOTS], y2k[SLOTS], ark[SLOTS];
        unsigned rk[SLOTS];
        bool act[SLOTS];
        #pragma unroll
        for (int k = 0; k < SLOTS; ++k) {
            act[k] = (sb0 + k) < TOPK;
            int s = act[k] ? (sb0 + k) : sb0;
            float4 bk = sbox[base + s];
            x1k[k] = bk.x; y1k[k] = bk.y; x2k[k] = bk.z; y2k[k] = bk.w;
            ark[k] = (bk.z - bk.x) * (bk.w - bk.y);
            rk[k] = sidx[base + s];
        }
        int b1 = bucketOf(x1k[0]);                // min bucket (slot-monotone)
        int b2m = bucketOf(x2k[0]);
        float gymin = y1k[0], gymax = y2k[0];
        #pragma unroll
        for (int k = 1; k < SLOTS; ++k)
            if (act[k]) {
                int b = bucketOf(x2k[k]); if (b > b2m) b2m = b;
                gymin = fminf(gymin, y1k[k]);
                gymax = fmaxf(gymax, y2k[k]);
            }
        const unsigned* bo = bofs + img * 130;
        unsigned s0 = bo[b1], s1 = bo[b2m + 1];
        if (s0 < s1) {
            unsigned nit = (s1 - s0 + 63) >> 6;
            unsigned c0 = s0 + (unsigned)lane;
            if (c0 > s1 - 1) c0 = s1 - 1;         // clamp: always valid
            float4 cb = sbox[base + c0];
            unsigned cr = sidx[base + c0];
            for (unsigned it = 0; it < nit; ++it) {
                float4 nb = cb; unsigned nr = cr;
                if (it + 1 < nit) {               // uniform prefetch
                    unsigned cn = s0 + (it + 1) * 64 + (unsigned)lane;
                    if (cn > s1 - 1) cn = s1 - 1;
                    nb = sbox[base + cn];
                    nr = sidx[base + cn];
                }
                bool in = (s0 + it * 64 + (unsigned)lane) < s1;
                bool yok = in && (cb.w > gymin) && (cb.y < gymax);
                float bar = (cb.z - cb.x) * (cb.w - cb.y);
                #pragma unroll
                for (int k = 0; k < SLOTS; ++k) {
                    bool hit = false;
                    unsigned edge = 0;
                    if (yok && act[k] && cb.x >= x1k[k]
                        && !(cb.x == x1k[k] && cr <= rk[k])) {
                        float dx = fminf(x2k[k], cb.z) - fmaxf(x1k[k], cb.x);
                        if (dx > 0.0f) {
                            float dy = fminf(y2k[k], cb.w) - fmaxf(y1k[k], cb.y);
                            if (dy > 0.0f) {
                                float inter = dx * dy;
                                float iou = inter / (bar + ark[k] - inter);
                                if (iou > 0.3f) {
                                    unsigned su = (rk[k] < cr) ? rk[k] : cr;
                                    unsigned vi = (rk[k] < cr) ? cr : rk[k];
                                    edge = (vi << 13) | su;
                                    hit = true;
                                }
                            }
                        }
                    }
                    unsigned long long bal = __ballot(hit);
                    if (bal) {
                        int n = __popcll(bal);
                        unsigned wb = 0;
                        if (lane == 0) wb = atomicAdd(&ecl, (unsigned)n);
                        wb = __shfl(wb, 0, 64);
                        if (hit) {
                            unsigned long long lt =
                                (lane == 0) ? 0ull : ((1ull << lane) - 1ull);
                            unsigned p = wb + (unsigned)__popcll(bal & lt);
                            if (p < (unsigned)EBUF) ebuf[p] = edge;
                            else {
                                unsigned gp = atomicAdd(ec, 1u);
                                if (gp < (unsigned)CAPE) eg[gp] = edge;
                            }
                        }
                    }
                }
                cb = nb; cr = nr;
            }
        }
    }
    __syncthreads();
    unsigned n = min(ecl, (unsigned)EBUF);
    if (threadIdx.x == 0 && n) ebase = atomicAdd(ec, n);
    __syncthreads();
    for (unsigned i = threadIdx.x; i < n; i += 256) {
        unsigned p = ebase + i;
        if (p < (unsigned)CAPE) eg[p] = ebuf[i];
    }
}

// K8: edge-parallel monotone fixpoint NMS resolve + compaction. Output slice
// already zeroed by k_bscat. ELDS 14336 (56 KiB) keeps larger edge sets
// LDS-resident across rounds.
__global__ void __launch_bounds__(256) k_nms3(
        const float* __restrict__ SC, const float4* __restrict__ BOX4,
        const unsigned* __restrict__ ecnt, const unsigned* __restrict__ edges,
        float* __restrict__ out) {
    __shared__ unsigned lgrp[ELDS];               // 56 KiB raw edge copy
    __shared__ unsigned undL[160], keptL[160], blockL[160];
    __shared__ unsigned pfx[80];
    __shared__ int chg[2];
    int img = blockIdx.x;
    int tid = threadIdx.x;
    int l = tid & 63;
    int wid = tid >> 6;
    size_t ib = (size_t)img * TOPK;
    const float* sc = SC + ib;

    if (tid < 160) { keptL[tid] = 0u; blockL[tid] = 0u; }
    if (tid < 2) chg[tid] = 0;
    for (int w = wid; w < NWORDS; w += 4) {
        int row = w * 64 + l;
        bool valid = (row < TOPK) && (sc[row] > 0.01f);
        unsigned long long b = __ballot(valid);
        if (l == 0) {
            undL[2 * w]     = (unsigned)b;
            undL[2 * w + 1] = (unsigned)(b >> 32);
        }
    }
    unsigned E = min(ecnt[(size_t)img * GSTRIDE], (unsigned)CAPE);
    const unsigned* eimg = edges + (size_t)img * CAPE;
    bool inl = (E <= (unsigned)ELDS);             // uniform across block
    if (inl) for (unsigned e = tid; e < E; e += 256) lgrp[e] = eimg[e];
    __syncthreads();

    for (int round = 0; round < 256; ++round) {
        int par = round & 1;
        for (unsigned e = tid; e < E; e += 256) {
            unsigned ed = inl ? lgrp[e] : eimg[e];
            unsigned s = ed & 8191u;
            unsigned v = ed >> 13;
            unsigned sw = s >> 5, sb = s & 31u;
            unsigned vw = v >> 5, vb = 1u << (v & 31u);
            if ((keptL[sw] >> sb) & 1u) {
                if (undL[vw] & vb) {
                    unsigned old = atomicAnd(&undL[vw], ~vb);
                    if (old & vb) chg[par] = 1;   // a real kill happened
                }
            } else if ((undL[sw] >> sb) & 1u) {
                if (!(blockL[vw] & vb)) atomicOr(&blockL[vw], vb);
            }
        }
        __syncthreads();
        if (tid < NW32) {
            unsigned nk = undL[tid] & ~blockL[tid];
            if (nk) {
                keptL[tid] |= nk;
                undL[tid] &= ~nk;
                chg[par] = 1;
            }
            blockL[tid] = 0u;
        }
        if (tid == 0) chg[par ^ 1] = 0;           // pre-zero next round's flag
        __syncthreads();
        if (!chg[par]) break;                     // uniform
    }

    if (tid == 0) {
        unsigned acc = 0;
        for (int w = 0; w < NWORDS; ++w) {
            pfx[w] = acc;
            acc += (unsigned)(__popc(keptL[2 * w]) + __popc(keptL[2 * w + 1]));
        }
    }
    __syncthreads();
    const float4* bx = BOX4 + ib;
    float* op = out + (((size_t)img * 2) + 1) * TOPK * 5;
    for (int w = wid; w < NWORDS; w += 4) {
        unsigned long long kw =
            ((unsigned long long)keptL[2 * w + 1] << 32) | keptL[2 * w];
        if (!kw) continue;
        int row = w * 64 + l;
        if ((kw >> l) & 1ull) {
            int rank = (int)pfx[w] + (int)__popcll(kw & ((1ull << l) - 1ull));
            float4 b = bx[row];
            float* r = op + (size_t)rank * 5;
            r[0] = sc[row]; r[1] = b.x; r[2] = b.y; r[3] = b.z; r[4] = b.w;
        }
    }
}

extern "C" void kernel_launch(void* const* d_in, const int* in_sizes, int n_in,
                              void* d_out, int out_size, void* d_ws, size_t ws_size,
                              hipStream_t stream) {
    (void)in_sizes; (void)n_in; (void)ws_size; (void)out_size;
    const float* loc  = (const float*)d_in[0];   // (16, 136500, 4)
    const float* conf = (const float*)d_in[1];   // (16*136500, 2)
    const float* pri  = (const float*)d_in[2];   // (136500, 4)
    float* out = (float*)d_out;                  // (16, 2, 5000, 5)
    char* ws = (char*)d_ws;

    float* SC   = (float*)(ws + OFF_SC);
    float4* BOX4 = (float4*)(ws + OFF_BOX4);
    unsigned* hist = (unsigned*)(ws + OFF_HIST);
    unsigned* cut  = (unsigned*)(ws + OFF_CUT);
    unsigned* sbase = (unsigned*)(ws + OFF_SBASE);
    unsigned* gbcur = (unsigned*)(ws + OFF_GBCUR);
    unsigned long long* keys = (unsigned long long*)(ws + OFF_KEYS);
    unsigned* ecnt = (unsigned*)(ws + OFF_ECNT);
    unsigned* bcnt = (unsigned*)(ws + OFF_BCNT);
    unsigned* bcur = (unsigned*)(ws + OFF_BCUR);
    unsigned* wcnt = (unsigned*)(ws + OFF_WCNT);
    unsigned* wl   = (unsigned*)(ws + OFF_WL);
    unsigned* edges = (unsigned*)(ws + OFF_EDGE);
    unsigned* bofs = (unsigned*)(ws + OFF_BOFS);
    unsigned* sidx = (unsigned*)(ws + OFF_SIDX);
    float4* sbox = (float4*)(ws + OFF_SBOX);

    // single contiguous zero: hist, gbcur, ecnt, bcnt, bcur, wcnt
    hipMemsetAsync(ws + OFF_HIST, 0, OFF_ZEND - OFF_HIST, stream);

    dim3 gh1(16, BNUM);                          // 16 grid-stride blocks/image
    k_hist<<<gh1, 512, 0, stream>>>(conf, hist);
    k_cutoff2<<<BNUM, 256, 0, stream>>>(hist, cut, sbase, wl, wcnt);
    dim3 gh2((HPNUM + 255) / 256, BNUM);
    k_gather2<<<gh2, 256, 0, stream>>>(conf, cut, sbase, gbcur, keys);
    k_ssortdec<<<1024, 256, 0, stream>>>(keys, hist, sbase, wl, wcnt,
                                         loc, pri, SC, BOX4, bcnt);
    dim3 gb((TOPK + 255) / 256, BNUM);           // wide bucket scatter + out-zero
    k_bscat<<<gb, 256, 0, stream>>>(bcnt, bcur, BOX4, bofs, sidx, sbox, out);
    dim3 pg((TOPK + 4 * SLOTS - 1) / (4 * SLOTS), BNUM);  // 4 waves x 4 slots
    k_pair4<<<pg, 256, 0, stream>>>(bofs, sidx, sbox, ecnt, edges);
    k_nms3<<<BNUM, 256, 0, stream>>>(SC, BOX4, ecnt, edges, out);
}